// Round 1
// baseline (118.418 us; speedup 1.0000x reference)
//
#include <hip/hip_runtime.h>

#define BN 16
#define TN 32
#define NCLS 20
#define K2_BLOCKS 512
#define K2_THREADS 256

// ANCHORS / STRIDES (exact in fp32 — divisions by powers of two)
__constant__ float c_aw[3][3] = {
  {1.25f,  2.0f,   4.125f},
  {1.875f, 3.875f, 3.6875f},
  {3.625f, 4.875f, 11.65625f}
};
__constant__ float c_ah[3][3] = {
  {1.625f,  3.75f,   2.875f},
  {3.8125f, 2.8125f, 7.4375f},
  {2.8125f, 6.1875f, 10.1875f}
};

__device__ __forceinline__ float bce(float x, float t){
  // max(x,0) - x*t + log1p(exp(-|x|))
  return fmaxf(x, 0.0f) - x * t + log1pf(__expf(-fabsf(x)));
}

// ws layout (floats):
//   [lvl*8+0] box_corr   [lvl*8+1] obj_corr   [lvl*8+2] noobj_sub
//   [lvl*8+3] cls_corr   [lvl*8+4] count
//   [32 + blk*6 + (lvl*2+m)]  per-block partial base sums (m=0 box, m=1 noobj)

__global__ void k_targets(const float* __restrict__ p0, const float* __restrict__ p1,
                          const float* __restrict__ p2, const float* __restrict__ tg,
                          float* __restrict__ ws){
  const int level = blockIdx.x;
  const float* p  = (level == 0) ? p0 : (level == 1 ? p1 : p2);
  const int Hh    = (level == 0) ? 80 : (level == 1 ? 40 : 20);
  const int Ww    = Hh;
  const int HW    = Hh * Ww;

  const int tid = threadIdx.x;          // 0..511
  const int b   = tid >> 5;             // batch
  const int t   = tid & 31;             // target slot

  __shared__ int   lin_s[BN * TN];
  __shared__ float red[BN * TN];

  const float cls_f = tg[(b*TN + t)*5 + 0];
  const float tx    = tg[(b*TN + t)*5 + 1];
  const float ty    = tg[(b*TN + t)*5 + 2];
  const float tw    = tg[(b*TN + t)*5 + 3];
  const float th    = tg[(b*TN + t)*5 + 4];

  int gx = (int)floorf(tx * (float)Ww); gx = min(max(gx, 0), Ww - 1);
  int gy = (int)floorf(ty * (float)Hh); gy = min(max(gy, 0), Hh - 1);

  float best = -1.0f; int ba = 0;
  for (int a = 0; a < 3; ++a){
    float aw = c_aw[level][a], ah = c_ah[level][a];
    float inter = fminf(tw, aw) * fminf(th, ah);
    float iou = inter / (tw*th + aw*ah - inter + 1e-6f);
    if (iou > best){ best = iou; ba = a; }   // first-max wins, matches jnp.argmax
  }
  const bool valid_pre = best > 0.3f;
  const int  lin = (gy * Ww + gx) * 3 + ba;

  lin_s[tid] = valid_pre ? lin : -1;
  __syncthreads();
  bool valid = valid_pre;
  if (valid_pre){
    const int base_t = b * TN;
    for (int u = t + 1; u < TN; ++u)
      if (lin_s[base_t + u] == lin){ valid = false; break; }   // shadowed by later valid_pre target
  }

  float vals[5] = {0.f, 0.f, 0.f, 0.f, 0.f};
  if (valid){
    const float baw = c_aw[level][ba], bah = c_ah[level][ba];
    float tb[4];
    tb[0] = tx * (float)Ww - (float)gx;
    tb[1] = ty * (float)Hh - (float)gy;
    tb[2] = logf(tw / baw + 1e-6f);
    tb[3] = logf(th / bah + 1e-6f);
    const int cls = (int)cls_f;
    const size_t base = (size_t)(b*75 + ba*25) * HW + (size_t)(gy * Ww + gx);
    float box_corr = 0.f;
    for (int c = 0; c < 4; ++c){
      float x = p[base + (size_t)c * HW];
      float d = x - tb[c];
      box_corr += d*d - x*x;
    }
    float x4 = p[base + (size_t)4 * HW];
    float cls_corr = 0.f;
    for (int c = 0; c < NCLS; ++c){
      float x = p[base + (size_t)(5 + c) * HW];
      cls_corr += bce(x, (c == cls) ? 1.0f : 0.0f);
    }
    vals[0] = box_corr;
    vals[1] = bce(x4, 1.0f);
    vals[2] = bce(x4, 0.0f);
    vals[3] = cls_corr;
    vals[4] = 1.0f;
  }

  // block reduction of 5 metrics over 512 threads
  for (int m = 0; m < 5; ++m){
    __syncthreads();
    red[tid] = vals[m];
    __syncthreads();
    for (int s = 256; s > 0; s >>= 1){
      if (tid < s) red[tid] += red[tid + s];
      __syncthreads();
    }
    if (tid == 0) ws[level*8 + m] = red[0];
  }
}

__global__ void k_base(const float* __restrict__ p0, const float* __restrict__ p1,
                       const float* __restrict__ p2, float* __restrict__ ws){
  // vec4 counts per level: B*15 planes * (HW/4)
  const int M0 = BN * 15 * 1600;   // 384000
  const int M1 = BN * 15 * 400;    //  96000
  const int M2 = BN * 15 * 100;    //  24000
  const int Mtot = M0 + M1 + M2;   // 504000

  float acc[3][2] = {{0.f,0.f},{0.f,0.f},{0.f,0.f}};

  for (int v = blockIdx.x * blockDim.x + threadIdx.x; v < Mtot;
       v += gridDim.x * blockDim.x){
    int level, lv, HW4; const float* p;
    if (v < M0)            { level = 0; lv = v;            HW4 = 1600; p = p0; }
    else if (v < M0 + M1)  { level = 1; lv = v - M0;       HW4 = 400;  p = p1; }
    else                   { level = 2; lv = v - M0 - M1;  HW4 = 100;  p = p2; }
    int plane = lv / HW4;
    int o     = lv - plane * HW4;
    int bb    = plane / 15;
    int j     = plane - bb * 15;
    int a     = j / 5;
    int c     = j - a * 5;
    int ch    = a * 25 + c;
    const float4 x = ((const float4*)p)[(size_t)(bb*75 + ch) * HW4 + o];
    if (c < 4) acc[level][0] += x.x*x.x + x.y*x.y + x.z*x.z + x.w*x.w;
    else       acc[level][1] += bce(x.x,0.f) + bce(x.y,0.f) + bce(x.z,0.f) + bce(x.w,0.f);
  }

  __shared__ float red[K2_THREADS];
  float* outp = ws + 32 + blockIdx.x * 6;
  int idx = 0;
  for (int l = 0; l < 3; ++l){
    for (int m = 0; m < 2; ++m){
      __syncthreads();
      red[threadIdx.x] = acc[l][m];
      __syncthreads();
      for (int s = K2_THREADS/2; s > 0; s >>= 1){
        if (threadIdx.x < s) red[threadIdx.x] += red[threadIdx.x + s];
        __syncthreads();
      }
      if (threadIdx.x == 0) outp[idx] = red[0];
      idx++;
    }
  }
}

__global__ void k_final(const float* __restrict__ ws, float* __restrict__ out){
  __shared__ float red[256];
  __shared__ float fin[6];
  float acc[6] = {0.f,0.f,0.f,0.f,0.f,0.f};
  for (int i = threadIdx.x; i < K2_BLOCKS; i += 256){
    const float* pp = ws + 32 + i * 6;
    for (int m = 0; m < 6; ++m) acc[m] += pp[m];
  }
  for (int m = 0; m < 6; ++m){
    __syncthreads();
    red[threadIdx.x] = acc[m];
    __syncthreads();
    for (int s = 128; s > 0; s >>= 1){
      if (threadIdx.x < s) red[threadIdx.x] += red[threadIdx.x + s];
      __syncthreads();
    }
    if (threadIdx.x == 0) fin[m] = red[0];
  }
  __syncthreads();
  if (threadIdx.x == 0){
    const int Hs[3] = {80, 40, 20};
    float total = 0.f;
    for (int l = 0; l < 3; ++l){
      float Sbox  = fin[l*2 + 0] + ws[l*8 + 0];
      float obj   = ws[l*8 + 1];
      float noobj = fin[l*2 + 1] - ws[l*8 + 2];
      float clsl  = ws[l*8 + 3];
      float cnt   = ws[l*8 + 4];
      float n_obj   = cnt + 1e-6f;
      float cells   = (float)(BN * Hs[l] * Hs[l] * 3);
      float n_noobj = (cells - cnt) + 1e-6f;
      total += 0.05f * Sbox / n_obj
             + 1.5f  * (obj / n_obj + 0.5f * noobj / n_noobj)
             + 0.15f * clsl / n_obj;
    }
    out[0] = total;
  }
}

extern "C" void kernel_launch(void* const* d_in, const int* in_sizes, int n_in,
                              void* d_out, int out_size, void* d_ws, size_t ws_size,
                              hipStream_t stream) {
  const float* p0 = (const float*)d_in[0];
  const float* p1 = (const float*)d_in[1];
  const float* p2 = (const float*)d_in[2];
  const float* tg = (const float*)d_in[3];
  float* out = (float*)d_out;
  float* ws  = (float*)d_ws;   // needs (32 + K2_BLOCKS*6)*4 = 12416 bytes

  k_targets<<<3, BN*TN, 0, stream>>>(p0, p1, p2, tg, ws);
  k_base<<<K2_BLOCKS, K2_THREADS, 0, stream>>>(p0, p1, p2, ws);
  k_final<<<1, 256, 0, stream>>>(ws, out);
}